// Round 6
// baseline (39.008 us; speedup 1.0000x reference)
//
#include <hip/hip_runtime.h>

constexpr int NQ = 7;
constexpr int NL = 4;
constexpr int NG = NL * NQ;   // 28
constexpr int NCLS = 22;

// ---------------- cross-lane primitives: PROVEN ONLY ----------------
// DPP quad_perm (masks 1,2) + ds_swizzle XOR (masks 4,8,16). All R1/R4-proven.
// No inline asm (R2/R3/R5 lesson: "+v"/"=v" asm with equal-valued operands gets
// register-coalesced into self-swaps).
template<int CTRL>
__device__ __forceinline__ float fdpp(float v) {
    return __int_as_float(__builtin_amdgcn_mov_dpp(__float_as_int(v), CTRL, 0xF, 0xF, true));
}
template<int OFF>
__device__ __forceinline__ float fswz(float v) {
    return __int_as_float(__builtin_amdgcn_ds_swizzle(__float_as_int(v), OFF));
}
template<int M>
__device__ __forceinline__ float xorl(float v) {
    if      constexpr (M == 1)  return fdpp<0xB1>(v);    // quad_perm [1,0,3,2]
    else if constexpr (M == 2)  return fdpp<0x4E>(v);    // quad_perm [2,3,0,1]
    else if constexpr (M == 4)  return fswz<0x101F>(v);  // xor4
    else if constexpr (M == 8)  return fswz<0x201F>(v);  // xor8
    else                        return fswz<0x401F>(v);  // xor16
}

// ---------------- fused gate build: U' = U_rot @ RX(c,s) ----------------
// u[8] = {u00r,u00i,u01r,u01i,u10r,u10i,u11r,u11i} (wave-uniform s_load)
__device__ __forceinline__ void fuse(const float* __restrict__ u, float c, float s,
                                     float4& A, float4& B) {
    A.x = fmaf(c, u[0],  s * u[3]);  A.y = fmaf(c, u[1], -s * u[2]);
    A.z = fmaf(c, u[2],  s * u[1]);  A.w = fmaf(c, u[3], -s * u[0]);
    B.x = fmaf(c, u[4],  s * u[7]);  B.y = fmaf(c, u[5], -s * u[6]);
    B.z = fmaf(c, u[6],  s * u[5]);  B.w = fmaf(c, u[7], -s * u[4]);
}

// 2x2 gate on a lane-bit qubit (pair across lane mask M), applied to 4 amps
template<int M>
__device__ __forceinline__ void gateL(int lane, float4 A, float4 B,
                                      float ar[4], float ai[4]) {
    const bool hi = (lane & M) != 0;
    const float avr = hi ? B.z : A.x, avi = hi ? B.w : A.y;   // diag coeff
    const float awr = hi ? B.x : A.z, awi = hi ? B.y : A.w;   // off-diag coeff
    #pragma unroll
    for (int k = 0; k < 4; ++k) {
        const float wr = xorl<M>(ar[k]), wi = xorl<M>(ai[k]);
        const float nr = avr*ar[k] - avi*ai[k] + awr*wr - awi*wi;
        const float ni = avr*ai[k] + avi*ar[k] + awr*wi + awi*wr;
        ar[k] = nr; ai[k] = ni;
    }
}

// full 2x2 on a register pair (v = row0 amp, w = row1 amp)
__device__ __forceinline__ void gate2(float4 A, float4 B,
                                      float& vr, float& vi, float& wr, float& wi) {
    const float n0r = A.x*vr - A.y*vi + A.z*wr - A.w*wi;
    const float n0i = A.x*vi + A.y*vr + A.z*wi + A.w*wr;
    const float n1r = B.x*vr - B.y*vi + B.z*wr - B.w*wi;
    const float n1i = B.x*vi + B.y*vr + B.z*wi + B.w*wr;
    vr = n0r; vi = n0i; wr = n1r; wi = n1i;
}

// CNOT with lane-bit target MT, lane-bit control MC
template<int MT, int MC>
__device__ __forceinline__ void cnotLT(int lane, float ar[4], float ai[4]) {
    const bool c = (lane & MC) != 0;
    #pragma unroll
    for (int k = 0; k < 4; ++k) {
        const float wr = xorl<MT>(ar[k]), wi = xorl<MT>(ai[k]);
        ar[k] = c ? wr : ar[k];
        ai[k] = c ? wi : ai[k];
    }
}

// ---------------- setup: 28 batch-independent Rot matrices -> d_ws ----------------
__global__ __launch_bounds__(64) void rot_setup(const float* __restrict__ wts,
                                                float* __restrict__ ru) {
    int g = threadIdx.x;
    if (g < NG) {
        float phi = wts[g*3+0], th = wts[g*3+1], om = wts[g*3+2];
        float ct = __cosf(0.5f*th), st = __sinf(0.5f*th);
        float ap = 0.5f*(phi+om),  am = 0.5f*(phi-om);
        float cp = __cosf(ap), sp = __sinf(ap);
        float cm = __cosf(am), sm = __sinf(am);
        float* u = ru + g*8;
        u[0] =  cp*ct; u[1] = -sp*ct;   // u00 = ep*ct        (ep = cp - i sp)
        u[2] = -cm*st; u[3] = -sm*st;   // u01 = -conj(em)*st (em = cm - i sm)
        u[4] =  cm*st; u[5] = -sm*st;   // u10 = em*st
        u[6] =  cp*ct; u[7] =  sp*ct;   // u11 = conj(ep)*ct
    }
}

// ---------------- main kernel: TWO batch elements per wave ----------------
// element = lane>>5; within-half lane w = lane&31; local amp k = 0..3.
// amp index a = (w<<2)|k, bits a6..a0 = w4 w3 w2 w1 w0 k1 k0.
// qubit q <-> amp bit (6-q):  q0->w4(m16) q1->w3(m8) q2->w2(m4) q3->w1(m2)
//                             q4->w0(m1)  q5->k1(local) q6->k0(local)
__global__ __launch_bounds__(256) void reupload_kernel(
    const float* __restrict__ x,       // (B,7)
    const float* __restrict__ ru,      // (28,8) precomputed Rot matrices
    const float* __restrict__ fc1_w,   // (32,7)
    const float* __restrict__ fc1_b,   // (32,)
    const float* __restrict__ fc2_w,   // (22,32)
    const float* __restrict__ fc2_b,   // (22,)
    float* __restrict__ out,           // (B,22)
    int B)
{
    const int lane = threadIdx.x & 63;
    const int wl   = threadIdx.x & 31;          // within-half lane
    const int grp  = threadIdx.x >> 5;          // 32-group id in block (0..7)
    const int b    = blockIdx.x * 8 + grp;      // one element per 32-group
    if (b >= B) return;

    float c[NQ], s[NQ];
    #pragma unroll
    for (int q = 0; q < NQ; ++q) {
        float h = 0.5f * x[b*NQ + q];
        c[q] = __cosf(h); s[q] = __sinf(h);
    }

    // |0..0>: amp 0 lives at w=0,k=0
    float ar[4], ai[4];
    #pragma unroll
    for (int k = 0; k < 4; ++k) { ar[k] = 0.f; ai[k] = 0.f; }
    ar[0] = (wl == 0) ? 1.f : 0.f;

    #pragma unroll
    for (int l = 0; l < NL; ++l) {
        const float* rl = ru + l * (NQ * 8);
        float4 A, Bq;
        // fused Rot·RX per qubit (distinct-qubit gates commute; Rot∘RX order kept)
        fuse(rl +  0, c[0], s[0], A, Bq); gateL<16>(lane, A, Bq, ar, ai);  // q0
        fuse(rl +  8, c[1], s[1], A, Bq); gateL< 8>(lane, A, Bq, ar, ai);  // q1
        fuse(rl + 16, c[2], s[2], A, Bq); gateL< 4>(lane, A, Bq, ar, ai);  // q2
        fuse(rl + 24, c[3], s[3], A, Bq); gateL< 2>(lane, A, Bq, ar, ai);  // q3
        fuse(rl + 32, c[4], s[4], A, Bq); gateL< 1>(lane, A, Bq, ar, ai);  // q4
        fuse(rl + 40, c[5], s[5], A, Bq);                                  // q5: k1
        gate2(A, Bq, ar[0], ai[0], ar[2], ai[2]);
        gate2(A, Bq, ar[1], ai[1], ar[3], ai[3]);
        fuse(rl + 48, c[6], s[6], A, Bq);                                  // q6: k0
        gate2(A, Bq, ar[0], ai[0], ar[1], ai[1]);
        gate2(A, Bq, ar[2], ai[2], ar[3], ai[3]);

        // CNOT ring CNOT(q, q+1 mod 7), reference order q=0..6
        cnotLT<8,16>(lane, ar, ai);   // (0,1): ctrl w4, tgt w3
        cnotLT<4, 8>(lane, ar, ai);   // (1,2)
        cnotLT<2, 4>(lane, ar, ai);   // (2,3)
        cnotLT<1, 2>(lane, ar, ai);   // (3,4)
        {   // (4,5): ctrl w0 (lane&1), tgt k1 -> cond swap (0<->2),(1<->3)
            const bool cc = (lane & 1) != 0;
            float t;
            t = ar[0]; ar[0] = cc ? ar[2] : ar[0]; ar[2] = cc ? t : ar[2];
            t = ai[0]; ai[0] = cc ? ai[2] : ai[0]; ai[2] = cc ? t : ai[2];
            t = ar[1]; ar[1] = cc ? ar[3] : ar[1]; ar[3] = cc ? t : ar[3];
            t = ai[1]; ai[1] = cc ? ai[3] : ai[1]; ai[3] = cc ? t : ai[3];
        }
        {   // (5,6): ctrl k1, tgt k0 -> unconditional A2<->A3 (free reg rename)
            float t;
            t = ar[2]; ar[2] = ar[3]; ar[3] = t;
            t = ai[2]; ai[2] = ai[3]; ai[3] = t;
        }
        {   // (6,0): ctrl k0, tgt w4 -> amps k=1,3 swap across mask16 (uncond)
            ar[1] = xorl<16>(ar[1]); ai[1] = xorl<16>(ai[1]);
            ar[3] = xorl<16>(ar[3]); ai[3] = xorl<16>(ai[3]);
        }
    }

    // ---------- <Z_j> ----------
    float p[4];
    #pragma unroll
    for (int k = 0; k < 4; ++k) p[k] = ar[k]*ar[k] + ai[k]*ai[k];
    const float t01 = p[0] + p[1], t23 = p[2] + p[3];
    const float t = t01 + t23;
    float z[NQ];
    z[0] = (lane & 16) ? -t : t;
    z[1] = (lane &  8) ? -t : t;
    z[2] = (lane &  4) ? -t : t;
    z[3] = (lane &  2) ? -t : t;
    z[4] = (lane &  1) ? -t : t;
    z[5] = t01 - t23;                         // sign by k1
    z[6] = (p[0] - p[1]) + (p[2] - p[3]);     // sign by k0
    #pragma unroll
    for (int j = 0; j < NQ; ++j) {
        float v = z[j];
        v += xorl<1>(v);
        v += xorl<2>(v);
        v += xorl<4>(v);
        v += xorl<8>(v);
        v += xorl<16>(v);
        z[j] = v;   // full per-element sum in every lane of the half
    }

    // ---------- MLP 7 -> 32(relu) -> 22, per 32-lane half ----------
    __shared__ __align__(16) float hbuf[8][32];
    float acc1 = fc1_b[wl];
    #pragma unroll
    for (int j = 0; j < NQ; ++j) acc1 = fmaf(z[j], fc1_w[wl*NQ + j], acc1);
    hbuf[grp][wl] = fmaxf(acc1, 0.f);
    __builtin_amdgcn_wave_barrier();
    asm volatile("s_waitcnt lgkmcnt(0)" ::: "memory");
    __builtin_amdgcn_sched_barrier(0);

    float hv[32];
    #pragma unroll
    for (int i = 0; i < 8; ++i) {   // broadcast reads within each half
        float4 v4 = *reinterpret_cast<const float4*>(&hbuf[grp][i*4]);
        hv[i*4+0] = v4.x; hv[i*4+1] = v4.y; hv[i*4+2] = v4.z; hv[i*4+3] = v4.w;
    }
    const int k = (wl < NCLS) ? wl : 0;
    float acc2 = fc2_b[k];
    const float4* w4 = reinterpret_cast<const float4*>(fc2_w + k*32);
    #pragma unroll
    for (int i = 0; i < 8; ++i) {
        float4 wv = w4[i];
        acc2 = fmaf(hv[i*4+0], wv.x, acc2);
        acc2 = fmaf(hv[i*4+1], wv.y, acc2);
        acc2 = fmaf(hv[i*4+2], wv.z, acc2);
        acc2 = fmaf(hv[i*4+3], wv.w, acc2);
    }
    if (wl < NCLS) out[b*NCLS + wl] = acc2;
}

extern "C" void kernel_launch(void* const* d_in, const int* in_sizes, int n_in,
                              void* d_out, int out_size, void* d_ws, size_t ws_size,
                              hipStream_t stream) {
    const float* x     = (const float*)d_in[0];
    const float* wts   = (const float*)d_in[1];
    const float* fc1_w = (const float*)d_in[2];
    const float* fc1_b = (const float*)d_in[3];
    const float* fc2_w = (const float*)d_in[4];
    const float* fc2_b = (const float*)d_in[5];
    float* out = (float*)d_out;
    float* ru  = (float*)d_ws;   // 28*8 floats = 896 B

    rot_setup<<<1, 64, 0, stream>>>(wts, ru);

    const int B = in_sizes[0] / NQ;            // 16384
    const int grid = (B + 7) / 8;              // 8 elements per 256-thread block
    reupload_kernel<<<grid, 256, 0, stream>>>(x, ru, fc1_w, fc1_b, fc2_w, fc2_b, out, B);
}

// Round 7
// 34.871 us; speedup vs baseline: 1.1186x; 1.1186x over previous
//
#include <hip/hip_runtime.h>

constexpr int NQ = 7;
constexpr int NL = 4;
constexpr int NG = NL * NQ;   // 28
constexpr int NCLS = 22;

// ---------------- cross-lane primitives: PROVEN ONLY ----------------
// DPP quad_perm (masks 1,2) + ds_swizzle XOR (masks 4,8,16). All R1/R4/R6-proven.
// No inline asm (R2/R3/R5 lesson: asm operands holding equal values get
// register-coalesced into self-swaps).
template<int CTRL>
__device__ __forceinline__ float fdpp(float v) {
    return __int_as_float(__builtin_amdgcn_mov_dpp(__float_as_int(v), CTRL, 0xF, 0xF, true));
}
template<int OFF>
__device__ __forceinline__ float fswz(float v) {
    return __int_as_float(__builtin_amdgcn_ds_swizzle(__float_as_int(v), OFF));
}
template<int M>
__device__ __forceinline__ float xorl(float v) {
    if      constexpr (M == 1)  return fdpp<0xB1>(v);    // quad_perm [1,0,3,2]
    else if constexpr (M == 2)  return fdpp<0x4E>(v);    // quad_perm [2,3,0,1]
    else if constexpr (M == 4)  return fswz<0x101F>(v);  // xor4
    else if constexpr (M == 8)  return fswz<0x201F>(v);  // xor8
    else                        return fswz<0x401F>(v);  // xor16
}

// ---------------- fused gate build: U' = U_rot @ RX(c,s) ----------------
// u[8] = {u00r,u00i,u01r,u01i,u10r,u10i,u11r,u11i} (LDS broadcast read)
__device__ __forceinline__ void fuse(const float* __restrict__ u, float c, float s,
                                     float4& A, float4& B) {
    A.x = fmaf(c, u[0],  s * u[3]);  A.y = fmaf(c, u[1], -s * u[2]);
    A.z = fmaf(c, u[2],  s * u[1]);  A.w = fmaf(c, u[3], -s * u[0]);
    B.x = fmaf(c, u[4],  s * u[7]);  B.y = fmaf(c, u[5], -s * u[6]);
    B.z = fmaf(c, u[6],  s * u[5]);  B.w = fmaf(c, u[7], -s * u[4]);
}

// 2x2 gate on a lane-bit qubit (pair across lane mask M), applied to 4 amps
template<int M>
__device__ __forceinline__ void gateL(int lane, float4 A, float4 B,
                                      float ar[4], float ai[4]) {
    const bool hi = (lane & M) != 0;
    const float avr = hi ? B.z : A.x, avi = hi ? B.w : A.y;   // diag coeff
    const float awr = hi ? B.x : A.z, awi = hi ? B.y : A.w;   // off-diag coeff
    #pragma unroll
    for (int k = 0; k < 4; ++k) {
        const float wr = xorl<M>(ar[k]), wi = xorl<M>(ai[k]);
        const float nr = avr*ar[k] - avi*ai[k] + awr*wr - awi*wi;
        const float ni = avr*ai[k] + avi*ar[k] + awr*wi + awi*wr;
        ar[k] = nr; ai[k] = ni;
    }
}

// full 2x2 on a register pair (v = row0 amp, w = row1 amp)
__device__ __forceinline__ void gate2(float4 A, float4 B,
                                      float& vr, float& vi, float& wr, float& wi) {
    const float n0r = A.x*vr - A.y*vi + A.z*wr - A.w*wi;
    const float n0i = A.x*vi + A.y*vr + A.z*wi + A.w*wr;
    const float n1r = B.x*vr - B.y*vi + B.z*wr - B.w*wi;
    const float n1i = B.x*vi + B.y*vr + B.z*wi + B.w*wr;
    vr = n0r; vi = n0i; wr = n1r; wi = n1i;
}

// CNOT with lane-bit target MT, lane-bit control MC
template<int MT, int MC>
__device__ __forceinline__ void cnotLT(int lane, float ar[4], float ai[4]) {
    const bool c = (lane & MC) != 0;
    #pragma unroll
    for (int k = 0; k < 4; ++k) {
        const float wr = xorl<MT>(ar[k]), wi = xorl<MT>(ai[k]);
        ar[k] = c ? wr : ar[k];
        ai[k] = c ? wi : ai[k];
    }
}

// ---------------- main kernel: TWO batch elements per wave, single launch ----------------
// element = lane>>5; within-half lane w = lane&31; local amp k = 0..3.
// amp index a = (w<<2)|k, bits a6..a0 = w4 w3 w2 w1 w0 k1 k0.
// qubit q <-> amp bit (6-q):  q0->w4(m16) q1->w3(m8) q2->w2(m4) q3->w1(m2)
//                             q4->w0(m1)  q5->k1(local) q6->k0(local)
__global__ __launch_bounds__(256) void reupload_kernel(
    const float* __restrict__ x,       // (B,7)
    const float* __restrict__ wts,     // (4,7,3)
    const float* __restrict__ fc1_w,   // (32,7)
    const float* __restrict__ fc1_b,   // (32,)
    const float* __restrict__ fc2_w,   // (22,32)
    const float* __restrict__ fc2_b,   // (22,)
    float* __restrict__ out,           // (B,22)
    int B)
{
    // --- per-block: 28 batch-independent Rot matrices -> LDS (R1-proven) ---
    __shared__ __align__(16) float rotU[NG * 8];
    {
        const int tid = threadIdx.x;
        if (tid < NG) {
            float phi = wts[tid*3+0], th = wts[tid*3+1], om = wts[tid*3+2];
            float ct = __cosf(0.5f*th), st = __sinf(0.5f*th);
            float ap = 0.5f*(phi+om),  am = 0.5f*(phi-om);
            float cp = __cosf(ap), sp = __sinf(ap);
            float cm = __cosf(am), sm = __sinf(am);
            float* u = &rotU[tid*8];
            u[0] =  cp*ct; u[1] = -sp*ct;   // u00 = ep*ct        (ep = cp - i sp)
            u[2] = -cm*st; u[3] = -sm*st;   // u01 = -conj(em)*st (em = cm - i sm)
            u[4] =  cm*st; u[5] = -sm*st;   // u10 = em*st
            u[6] =  cp*ct; u[7] =  sp*ct;   // u11 = conj(ep)*ct
        }
    }
    __syncthreads();

    const int lane = threadIdx.x & 63;
    const int wl   = threadIdx.x & 31;          // within-half lane
    const int grp  = threadIdx.x >> 5;          // 32-group id in block (0..7)
    const int b    = blockIdx.x * 8 + grp;      // one element per 32-group
    if (b >= B) return;

    float c[NQ], s[NQ];
    #pragma unroll
    for (int q = 0; q < NQ; ++q) {
        float h = 0.5f * x[b*NQ + q];
        c[q] = __cosf(h); s[q] = __sinf(h);
    }

    // |0..0>: amp 0 lives at w=0,k=0
    float ar[4], ai[4];
    #pragma unroll
    for (int k = 0; k < 4; ++k) { ar[k] = 0.f; ai[k] = 0.f; }
    ar[0] = (wl == 0) ? 1.f : 0.f;

    #pragma unroll
    for (int l = 0; l < NL; ++l) {
        const float* rl = &rotU[l * (NQ * 8)];
        float4 A, Bq;
        // fused Rot·RX per qubit (distinct-qubit gates commute; Rot∘RX order kept)
        fuse(rl +  0, c[0], s[0], A, Bq); gateL<16>(lane, A, Bq, ar, ai);  // q0
        fuse(rl +  8, c[1], s[1], A, Bq); gateL< 8>(lane, A, Bq, ar, ai);  // q1
        fuse(rl + 16, c[2], s[2], A, Bq); gateL< 4>(lane, A, Bq, ar, ai);  // q2
        fuse(rl + 24, c[3], s[3], A, Bq); gateL< 2>(lane, A, Bq, ar, ai);  // q3
        fuse(rl + 32, c[4], s[4], A, Bq); gateL< 1>(lane, A, Bq, ar, ai);  // q4
        fuse(rl + 40, c[5], s[5], A, Bq);                                  // q5: k1
        gate2(A, Bq, ar[0], ai[0], ar[2], ai[2]);
        gate2(A, Bq, ar[1], ai[1], ar[3], ai[3]);
        fuse(rl + 48, c[6], s[6], A, Bq);                                  // q6: k0
        gate2(A, Bq, ar[0], ai[0], ar[1], ai[1]);
        gate2(A, Bq, ar[2], ai[2], ar[3], ai[3]);

        // CNOT ring CNOT(q, q+1 mod 7), reference order q=0..6
        cnotLT<8,16>(lane, ar, ai);   // (0,1): ctrl w4, tgt w3
        cnotLT<4, 8>(lane, ar, ai);   // (1,2)
        cnotLT<2, 4>(lane, ar, ai);   // (2,3)
        cnotLT<1, 2>(lane, ar, ai);   // (3,4)
        {   // (4,5): ctrl w0 (lane&1), tgt k1 -> cond swap (0<->2),(1<->3)
            const bool cc = (lane & 1) != 0;
            float t;
            t = ar[0]; ar[0] = cc ? ar[2] : ar[0]; ar[2] = cc ? t : ar[2];
            t = ai[0]; ai[0] = cc ? ai[2] : ai[0]; ai[2] = cc ? t : ai[2];
            t = ar[1]; ar[1] = cc ? ar[3] : ar[1]; ar[3] = cc ? t : ar[3];
            t = ai[1]; ai[1] = cc ? ai[3] : ai[1]; ai[3] = cc ? t : ai[3];
        }
        {   // (5,6): ctrl k1, tgt k0 -> unconditional A2<->A3 (free reg rename)
            float t;
            t = ar[2]; ar[2] = ar[3]; ar[3] = t;
            t = ai[2]; ai[2] = ai[3]; ai[3] = t;
        }
        {   // (6,0): ctrl k0, tgt w4 -> amps k=1,3 swap across mask16 (uncond)
            ar[1] = xorl<16>(ar[1]); ai[1] = xorl<16>(ai[1]);
            ar[3] = xorl<16>(ar[3]); ai[3] = xorl<16>(ai[3]);
        }
    }

    // ---------- <Z_j> ----------
    float p[4];
    #pragma unroll
    for (int k = 0; k < 4; ++k) p[k] = ar[k]*ar[k] + ai[k]*ai[k];
    const float t01 = p[0] + p[1], t23 = p[2] + p[3];
    const float t = t01 + t23;
    float z[NQ];
    z[0] = (lane & 16) ? -t : t;
    z[1] = (lane &  8) ? -t : t;
    z[2] = (lane &  4) ? -t : t;
    z[3] = (lane &  2) ? -t : t;
    z[4] = (lane &  1) ? -t : t;
    z[5] = t01 - t23;                         // sign by k1
    z[6] = (p[0] - p[1]) + (p[2] - p[3]);     // sign by k0
    #pragma unroll
    for (int j = 0; j < NQ; ++j) {
        float v = z[j];
        v += xorl<1>(v);
        v += xorl<2>(v);
        v += xorl<4>(v);
        v += xorl<8>(v);
        v += xorl<16>(v);
        z[j] = v;   // full per-element sum in every lane of the half
    }

    // ---------- MLP 7 -> 32(relu) -> 22, per 32-lane half ----------
    __shared__ __align__(16) float hbuf[8][32];
    float acc1 = fc1_b[wl];
    #pragma unroll
    for (int j = 0; j < NQ; ++j) acc1 = fmaf(z[j], fc1_w[wl*NQ + j], acc1);
    hbuf[grp][wl] = fmaxf(acc1, 0.f);
    __builtin_amdgcn_wave_barrier();
    asm volatile("s_waitcnt lgkmcnt(0)" ::: "memory");
    __builtin_amdgcn_sched_barrier(0);

    float hv[32];
    #pragma unroll
    for (int i = 0; i < 8; ++i) {   // broadcast reads within each half
        float4 v4 = *reinterpret_cast<const float4*>(&hbuf[grp][i*4]);
        hv[i*4+0] = v4.x; hv[i*4+1] = v4.y; hv[i*4+2] = v4.z; hv[i*4+3] = v4.w;
    }
    const int k = (wl < NCLS) ? wl : 0;
    float acc2 = fc2_b[k];
    const float4* w4 = reinterpret_cast<const float4*>(fc2_w + k*32);
    #pragma unroll
    for (int i = 0; i < 8; ++i) {
        float4 wv = w4[i];
        acc2 = fmaf(hv[i*4+0], wv.x, acc2);
        acc2 = fmaf(hv[i*4+1], wv.y, acc2);
        acc2 = fmaf(hv[i*4+2], wv.z, acc2);
        acc2 = fmaf(hv[i*4+3], wv.w, acc2);
    }
    if (wl < NCLS) out[b*NCLS + wl] = acc2;
}

extern "C" void kernel_launch(void* const* d_in, const int* in_sizes, int n_in,
                              void* d_out, int out_size, void* d_ws, size_t ws_size,
                              hipStream_t stream) {
    const float* x     = (const float*)d_in[0];
    const float* wts   = (const float*)d_in[1];
    const float* fc1_w = (const float*)d_in[2];
    const float* fc1_b = (const float*)d_in[3];
    const float* fc2_w = (const float*)d_in[4];
    const float* fc2_b = (const float*)d_in[5];
    float* out = (float*)d_out;

    const int B = in_sizes[0] / NQ;            // 16384
    const int grid = (B + 7) / 8;              // 8 elements per 256-thread block
    reupload_kernel<<<grid, 256, 0, stream>>>(x, wts, fc1_w, fc1_b, fc2_w, fc2_b, out, B);
}